// Round 1
// baseline (693.882 us; speedup 1.0000x reference)
//
#include <hip/hip_runtime.h>
#include <hip/hip_bf16.h>
#include <cstddef>

// ---------------------------------------------------------------------------
// 3-layer GAT (PyG-style) on MI355X.
// Strategy: per call -> build CSR by dst (histogram + scan + scatter), then per
// layer: fp32 tiled GEMM (h = x@W), compute attention logits al_s/al_d, then
// one wave per destination node does online-softmax aggregation (no atomics).
// ---------------------------------------------------------------------------

#define TILE_BM 128
#define TILE_BN 128
#define TILE_KB 16

// ---------------- CSR build ----------------

__global__ void zero_i32(int* __restrict__ p, int n) {
  int i = blockIdx.x * 256 + threadIdx.x;
  if (i < n) p[i] = 0;
}

__global__ void edge_histogram(const int* __restrict__ ei, int E, int nnodes,
                               int* __restrict__ counts) {
  int e = blockIdx.x * 256 + threadIdx.x;
  int tot = E + nnodes;
  if (e >= tot) return;
  int dst = (e < E) ? ei[E + e] : (e - E);
  atomicAdd(&counts[dst], 1);
}

// exclusive scan within 256-element blocks; block totals to sums (optional)
__global__ void scan_block(const int* __restrict__ in, int* __restrict__ out,
                           int* __restrict__ sums, int n) {
  __shared__ int tmp[256];
  int i = blockIdx.x * 256 + threadIdx.x;
  int v = (i < n) ? in[i] : 0;
  tmp[threadIdx.x] = v;
  __syncthreads();
  for (int off = 1; off < 256; off <<= 1) {
    int t = (threadIdx.x >= off) ? tmp[threadIdx.x - off] : 0;
    __syncthreads();
    tmp[threadIdx.x] += t;
    __syncthreads();
  }
  if (i < n) out[i] = tmp[threadIdx.x] - v;  // exclusive
  if (sums && threadIdx.x == 255) sums[blockIdx.x] = tmp[255];
}

__global__ void add_offsets(int* __restrict__ row_ptr, const int* __restrict__ offs,
                            int* __restrict__ nextp, int n, int total) {
  int i = blockIdx.x * 256 + threadIdx.x;
  if (i < n) {
    int v = row_ptr[i] + offs[blockIdx.x];
    row_ptr[i] = v;
    nextp[i] = v;
  }
  if (i == 0) row_ptr[n] = total;
}

__global__ void edge_scatter(const int* __restrict__ ei, int E, int nnodes,
                             int* __restrict__ nextp, int* __restrict__ col_idx) {
  int e = blockIdx.x * 256 + threadIdx.x;
  int tot = E + nnodes;
  if (e >= tot) return;
  int src = (e < E) ? ei[e] : (e - E);
  int dst = (e < E) ? ei[E + e] : (e - E);
  int pos = atomicAdd(&nextp[dst], 1);
  col_idx[pos] = src;
}

// ---------------- fp32 GEMM: C[M,N] = A[M,K] @ B[K,N] ----------------
// 128x128 block tile, 256 threads, 8x8 per thread (split 4+4 to avoid LDS
// bank conflicts: reads at tx*4 / 64+tx*4 are 2-way aliased = free).

__global__ __launch_bounds__(256) void gemm_f32(const float* __restrict__ A,
                                                const float* __restrict__ B,
                                                float* __restrict__ C,
                                                int M, int N, int K) {
  __shared__ float As[TILE_KB][TILE_BM + 4];
  __shared__ float Bs[TILE_KB][TILE_BN];
  int t = threadIdx.x;
  int m0 = blockIdx.x * TILE_BM;
  int n0 = blockIdx.y * TILE_BN;
  int tx = t & 15, ty = t >> 4;

  float c[2][2][4][4];
#pragma unroll
  for (int a = 0; a < 2; ++a)
#pragma unroll
    for (int b = 0; b < 2; ++b)
#pragma unroll
      for (int i = 0; i < 4; ++i)
#pragma unroll
        for (int j = 0; j < 4; ++j) c[a][b][i][j] = 0.f;

  for (int k0 = 0; k0 < K; k0 += TILE_KB) {
    // A tile: 128 rows x 16 k, transposed into As[k][m]
#pragma unroll
    for (int r = 0; r < 2; ++r) {
      int idx = t + r * 256;
      int row = idx >> 2;   // 0..127
      int quad = idx & 3;   // 0..3 -> k sub-quad
      float4 v = {0.f, 0.f, 0.f, 0.f};
      int gr = m0 + row;
      if (gr < M) v = *(const float4*)&A[(size_t)gr * K + k0 + quad * 4];
      As[quad * 4 + 0][row] = v.x;
      As[quad * 4 + 1][row] = v.y;
      As[quad * 4 + 2][row] = v.z;
      As[quad * 4 + 3][row] = v.w;
    }
    // B tile: 16 k-rows x 128 cols
#pragma unroll
    for (int r = 0; r < 2; ++r) {
      int idx = t + r * 256;
      int krow = idx >> 5;  // 0..15
      int q = idx & 31;     // col quad
      float4 v = *(const float4*)&B[(size_t)(k0 + krow) * N + n0 + q * 4];
      *(float4*)&Bs[krow][q * 4] = v;
    }
    __syncthreads();
#pragma unroll
    for (int k = 0; k < TILE_KB; ++k) {
      float4 a0 = *(const float4*)&As[k][ty * 4];
      float4 a1 = *(const float4*)&As[k][64 + ty * 4];
      float4 b0 = *(const float4*)&Bs[k][tx * 4];
      float4 b1 = *(const float4*)&Bs[k][64 + tx * 4];
      float av[2][4] = {{a0.x, a0.y, a0.z, a0.w}, {a1.x, a1.y, a1.z, a1.w}};
      float bv[2][4] = {{b0.x, b0.y, b0.z, b0.w}, {b1.x, b1.y, b1.z, b1.w}};
#pragma unroll
      for (int ih = 0; ih < 2; ++ih)
#pragma unroll
        for (int jh = 0; jh < 2; ++jh)
#pragma unroll
          for (int i = 0; i < 4; ++i)
#pragma unroll
            for (int j = 0; j < 4; ++j)
              c[ih][jh][i][j] += av[ih][i] * bv[jh][j];
    }
    __syncthreads();
  }
#pragma unroll
  for (int ih = 0; ih < 2; ++ih)
#pragma unroll
    for (int i = 0; i < 4; ++i) {
      int gr = m0 + ih * 64 + ty * 4 + i;
      if (gr >= M) continue;
#pragma unroll
      for (int jh = 0; jh < 2; ++jh) {
        float4 v = {c[ih][jh][i][0], c[ih][jh][i][1], c[ih][jh][i][2],
                    c[ih][jh][i][3]};
        *(float4*)&C[(size_t)gr * N + n0 + jh * 64 + tx * 4] = v;
      }
    }
}

// ---------------- attention logits: al_s/al_d [N,4] from h [N,256] ----------

__global__ __launch_bounds__(256) void compute_al(const float* __restrict__ h,
                                                  const float* __restrict__ a_src,
                                                  const float* __restrict__ a_dst,
                                                  float* __restrict__ al_s,
                                                  float* __restrict__ al_d,
                                                  int nnodes) {
  int n = blockIdx.x * 4 + (threadIdx.x >> 6);
  if (n >= nnodes) return;
  int l = threadIdx.x & 63;
  float4 hv = *(const float4*)&h[(size_t)n * 256 + l * 4];
  float4 as4 = *(const float4*)&a_src[l * 4];
  float4 ad4 = *(const float4*)&a_dst[l * 4];
  float ps = hv.x * as4.x + hv.y * as4.y + hv.z * as4.z + hv.w * as4.w;
  float pd = hv.x * ad4.x + hv.y * ad4.y + hv.z * ad4.z + hv.w * ad4.w;
#pragma unroll
  for (int off = 1; off < 16; off <<= 1) {
    ps += __shfl_xor(ps, off);
    pd += __shfl_xor(pd, off);
  }
  if ((l & 15) == 0) {
    al_s[n * 4 + (l >> 4)] = ps;
    al_d[n * 4 + (l >> 4)] = pd;
  }
}

// ---------------- per-dst online-softmax aggregation (heads=4, C=64) --------

template <bool RELU>
__global__ __launch_bounds__(256) void gat_aggregate(
    const float* __restrict__ h, const float* __restrict__ al_s,
    const float* __restrict__ al_d, const int* __restrict__ row_ptr,
    const int* __restrict__ col_idx, const float* __restrict__ bias,
    float* __restrict__ out, int nnodes) {
  int n = blockIdx.x * 4 + (threadIdx.x >> 6);
  if (n >= nnodes) return;
  int l = threadIdx.x & 63;
  int hd = l >> 4;
  float ad = al_d[n * 4 + hd];
  int beg = row_ptr[n], end = row_ptr[n + 1];
  float m = -3.0e38f, s = 0.f;
  float4 acc = {0.f, 0.f, 0.f, 0.f};
  for (int j = beg; j < end; ++j) {
    int src = col_idx[j];
    float e = al_s[src * 4 + hd] + ad;
    e = fmaxf(e, 0.2f * e);  // leaky_relu(0.2)
    float mn = fmaxf(m, e);
    float sc = __expf(m - mn);
    float p = __expf(e - mn);
    s = s * sc + p;
    float4 hv = *(const float4*)&h[(size_t)src * 256 + l * 4];
    acc.x = acc.x * sc + p * hv.x;
    acc.y = acc.y * sc + p * hv.y;
    acc.z = acc.z * sc + p * hv.z;
    acc.w = acc.w * sc + p * hv.w;
    m = mn;
  }
  float inv = 1.f / (s + 1e-16f);
  float4 bv = *(const float4*)&bias[l * 4];
  float4 o = {acc.x * inv + bv.x, acc.y * inv + bv.y, acc.z * inv + bv.z,
              acc.w * inv + bv.w};
  if (RELU) {
    o.x = fmaxf(o.x, 0.f);
    o.y = fmaxf(o.y, 0.f);
    o.z = fmaxf(o.z, 0.f);
    o.w = fmaxf(o.w, 0.f);
  }
  *(float4*)&out[(size_t)n * 256 + l * 4] = o;
}

// ---------------- layer 3: tiny GEMM (256->5) fused with al3 ----------------

__global__ __launch_bounds__(256) void gemm3_al(const float* __restrict__ Hin,
                                                const float* __restrict__ W3,
                                                const float* __restrict__ a_src3,
                                                const float* __restrict__ a_dst3,
                                                float* __restrict__ h3,
                                                float* __restrict__ al_s,
                                                float* __restrict__ al_d,
                                                int nnodes) {
  int n = blockIdx.x * 4 + (threadIdx.x >> 6);
  if (n >= nnodes) return;
  int l = threadIdx.x & 63;
  float4 hv = *(const float4*)&Hin[(size_t)n * 256 + l * 4];
  float acc[5];
#pragma unroll
  for (int cc = 0; cc < 5; ++cc) {
    acc[cc] = hv.x * W3[(l * 4 + 0) * 5 + cc] + hv.y * W3[(l * 4 + 1) * 5 + cc] +
              hv.z * W3[(l * 4 + 2) * 5 + cc] + hv.w * W3[(l * 4 + 3) * 5 + cc];
  }
#pragma unroll
  for (int cc = 0; cc < 5; ++cc)
#pragma unroll
    for (int off = 32; off; off >>= 1) acc[cc] += __shfl_xor(acc[cc], off);
  if (l == 0) {
    float as = 0.f, adv = 0.f;
#pragma unroll
    for (int cc = 0; cc < 5; ++cc) {
      h3[(size_t)n * 5 + cc] = acc[cc];
      as += acc[cc] * a_src3[cc];
      adv += acc[cc] * a_dst3[cc];
    }
    al_s[n] = as;
    al_d[n] = adv;
  }
}

__global__ __launch_bounds__(256) void gat_aggregate3(
    const float* __restrict__ h3, const float* __restrict__ al_s,
    const float* __restrict__ al_d, const int* __restrict__ row_ptr,
    const int* __restrict__ col_idx, const float* __restrict__ b3,
    float* __restrict__ out, int nnodes) {
  int n = blockIdx.x * 4 + (threadIdx.x >> 6);
  if (n >= nnodes) return;
  int l = threadIdx.x & 63;
  float ad = al_d[n];
  int beg = row_ptr[n], end = row_ptr[n + 1];
  float m = -3.0e38f, s = 0.f, acc = 0.f;
  for (int j = beg; j < end; ++j) {
    int src = col_idx[j];
    float e = al_s[src] + ad;
    e = fmaxf(e, 0.2f * e);
    float mn = fmaxf(m, e);
    float sc = __expf(m - mn);
    float p = __expf(e - mn);
    s = s * sc + p;
    float hv = (l < 5) ? h3[(size_t)src * 5 + l] : 0.f;
    acc = acc * sc + p * hv;
    m = mn;
  }
  if (l < 5) out[(size_t)n * 5 + l] = acc / (s + 1e-16f) + b3[l];
}

// ---------------- launch ----------------

extern "C" void kernel_launch(void* const* d_in, const int* in_sizes, int n_in,
                              void* d_out, int out_size, void* d_ws, size_t ws_size,
                              hipStream_t stream) {
  const float* x = (const float*)d_in[0];
  const int* ei = (const int*)d_in[1];
  const float* W1 = (const float*)d_in[2];
  const float* as1 = (const float*)d_in[3];
  const float* ad1 = (const float*)d_in[4];
  const float* b1 = (const float*)d_in[5];
  const float* W2 = (const float*)d_in[6];
  const float* as2 = (const float*)d_in[7];
  const float* ad2 = (const float*)d_in[8];
  const float* b2 = (const float*)d_in[9];
  const float* W3 = (const float*)d_in[10];
  const float* as3 = (const float*)d_in[11];
  const float* ad3 = (const float*)d_in[12];
  const float* b3 = (const float*)d_in[13];

  int N = in_sizes[0] / 128;  // 50000
  int E = in_sizes[1] / 2;    // 800000
  int tot = E + N;            // 850000

  char* w = (char*)d_ws;
  size_t off = 0;
  auto alloc = [&](size_t bytes) -> void* {
    void* p = w + off;
    off += (bytes + 255) & ~(size_t)255;
    return p;
  };
  float* bufA = (float*)alloc((size_t)N * 256 * 4);
  float* bufB = (float*)alloc((size_t)N * 256 * 4);
  float* h3 = (float*)alloc((size_t)N * 5 * 4);
  float* alS = (float*)alloc((size_t)N * 4 * 4);
  float* alD = (float*)alloc((size_t)N * 4 * 4);
  int* row_ptr = (int*)alloc(((size_t)N + 1) * 4);
  int* nextp = (int*)alloc((size_t)N * 4);
  int* bsums = (int*)alloc(256 * 4);
  int* col_idx = (int*)alloc((size_t)tot * 4);
  (void)ws_size;

  int nbN = (N + 255) / 256;   // 196
  int nbE = (tot + 255) / 256; // 3321
  int nb4 = (N + 3) / 4;       // 12500

  // CSR build (counts live in nextp)
  zero_i32<<<nbN, 256, 0, stream>>>(nextp, N);
  edge_histogram<<<nbE, 256, 0, stream>>>(ei, E, N, nextp);
  scan_block<<<nbN, 256, 0, stream>>>(nextp, row_ptr, bsums, N);
  scan_block<<<1, 256, 0, stream>>>(bsums, bsums, nullptr, nbN);
  add_offsets<<<nbN, 256, 0, stream>>>(row_ptr, bsums, nextp, N, tot);
  edge_scatter<<<nbE, 256, 0, stream>>>(ei, E, N, nextp, col_idx);

  dim3 g1((N + TILE_BM - 1) / TILE_BM, 256 / TILE_BN);

  // layer 1
  gemm_f32<<<g1, 256, 0, stream>>>(x, W1, bufA, N, 256, 128);
  compute_al<<<nb4, 256, 0, stream>>>(bufA, as1, ad1, alS, alD, N);
  gat_aggregate<true><<<nb4, 256, 0, stream>>>(bufA, alS, alD, row_ptr, col_idx,
                                               b1, bufB, N);
  // layer 2
  gemm_f32<<<g1, 256, 0, stream>>>(bufB, W2, bufA, N, 256, 256);
  compute_al<<<nb4, 256, 0, stream>>>(bufA, as2, ad2, alS, alD, N);
  gat_aggregate<true><<<nb4, 256, 0, stream>>>(bufA, alS, alD, row_ptr, col_idx,
                                               b2, bufB, N);
  // layer 3
  gemm3_al<<<nb4, 256, 0, stream>>>(bufB, W3, as3, ad3, h3, alS, alD, N);
  gat_aggregate3<<<nb4, 256, 0, stream>>>(h3, alS, alD, row_ptr, col_idx, b3,
                                          (float*)d_out, N);
}

// Round 3
// 686.758 us; speedup vs baseline: 1.0104x; 1.0104x over previous
//
#include <hip/hip_runtime.h>
#include <hip/hip_bf16.h>
#include <cstddef>

// ---------------------------------------------------------------------------
// 3-layer GAT (PyG-style) on MI355X.
// Per call: build CSR by dst (histogram + scan + scatter), then per layer:
// fp32 tiled GEMM (h = x@W), attention logits al_s/al_d, then one wave per
// destination node does two-pass softmax aggregation (no atomics):
//   pass 1: 16 edges in parallel compute e -> LDS, shuffle-reduce max
//   pass 2: unrolled x4 gather of h[src] rows, independent FMA accumulate
// ---------------------------------------------------------------------------

#define TILE_BM 128
#define TILE_BN 128
#define TILE_KB 16
#define ECAP 96  // LDS-cached logits per node; deg>ECAP falls back to re-gather

// ---------------- CSR build ----------------

__global__ void zero_i32(int* __restrict__ p, int n) {
  int i = blockIdx.x * 256 + threadIdx.x;
  if (i < n) p[i] = 0;
}

__global__ void edge_histogram(const int* __restrict__ ei, int E, int nnodes,
                               int* __restrict__ counts) {
  int e = blockIdx.x * 256 + threadIdx.x;
  int tot = E + nnodes;
  if (e >= tot) return;
  int dst = (e < E) ? ei[E + e] : (e - E);
  atomicAdd(&counts[dst], 1);
}

__global__ void scan_block(const int* __restrict__ in, int* __restrict__ out,
                           int* __restrict__ sums, int n) {
  __shared__ int tmp[256];
  int i = blockIdx.x * 256 + threadIdx.x;
  int v = (i < n) ? in[i] : 0;
  tmp[threadIdx.x] = v;
  __syncthreads();
  for (int off = 1; off < 256; off <<= 1) {
    int t = (threadIdx.x >= off) ? tmp[threadIdx.x - off] : 0;
    __syncthreads();
    tmp[threadIdx.x] += t;
    __syncthreads();
  }
  if (i < n) out[i] = tmp[threadIdx.x] - v;  // exclusive
  if (sums && threadIdx.x == 255) sums[blockIdx.x] = tmp[255];
}

__global__ void add_offsets(int* __restrict__ row_ptr, const int* __restrict__ offs,
                            int* __restrict__ nextp, int n, int total) {
  int i = blockIdx.x * 256 + threadIdx.x;
  if (i < n) {
    int v = row_ptr[i] + offs[blockIdx.x];
    row_ptr[i] = v;
    nextp[i] = v;
  }
  if (i == 0) row_ptr[n] = total;
}

__global__ void edge_scatter(const int* __restrict__ ei, int E, int nnodes,
                             int* __restrict__ nextp, int* __restrict__ col_idx) {
  int e = blockIdx.x * 256 + threadIdx.x;
  int tot = E + nnodes;
  if (e >= tot) return;
  int src = (e < E) ? ei[e] : (e - E);
  int dst = (e < E) ? ei[E + e] : (e - E);
  int pos = atomicAdd(&nextp[dst], 1);
  col_idx[pos] = src;
}

// ---------------- fp32 GEMM: C[M,N] = A[M,K] @ B[K,N] ----------------

__global__ __launch_bounds__(256) void gemm_f32(const float* __restrict__ A,
                                                const float* __restrict__ B,
                                                float* __restrict__ C,
                                                int M, int N, int K) {
  __shared__ float As[TILE_KB][TILE_BM + 4];
  __shared__ float Bs[TILE_KB][TILE_BN];
  int t = threadIdx.x;
  int m0 = blockIdx.x * TILE_BM;
  int n0 = blockIdx.y * TILE_BN;
  int tx = t & 15, ty = t >> 4;

  float c[2][2][4][4];
#pragma unroll
  for (int a = 0; a < 2; ++a)
#pragma unroll
    for (int b = 0; b < 2; ++b)
#pragma unroll
      for (int i = 0; i < 4; ++i)
#pragma unroll
        for (int j = 0; j < 4; ++j) c[a][b][i][j] = 0.f;

  for (int k0 = 0; k0 < K; k0 += TILE_KB) {
#pragma unroll
    for (int r = 0; r < 2; ++r) {
      int idx = t + r * 256;
      int row = idx >> 2;
      int quad = idx & 3;
      float4 v = {0.f, 0.f, 0.f, 0.f};
      int gr = m0 + row;
      if (gr < M) v = *(const float4*)&A[(size_t)gr * K + k0 + quad * 4];
      As[quad * 4 + 0][row] = v.x;
      As[quad * 4 + 1][row] = v.y;
      As[quad * 4 + 2][row] = v.z;
      As[quad * 4 + 3][row] = v.w;
    }
#pragma unroll
    for (int r = 0; r < 2; ++r) {
      int idx = t + r * 256;
      int krow = idx >> 5;
      int q = idx & 31;
      float4 v = *(const float4*)&B[(size_t)(k0 + krow) * N + n0 + q * 4];
      *(float4*)&Bs[krow][q * 4] = v;
    }
    __syncthreads();
#pragma unroll
    for (int k = 0; k < TILE_KB; ++k) {
      float4 a0 = *(const float4*)&As[k][ty * 4];
      float4 a1 = *(const float4*)&As[k][64 + ty * 4];
      float4 b0 = *(const float4*)&Bs[k][tx * 4];
      float4 b1 = *(const float4*)&Bs[k][64 + tx * 4];
      float av[2][4] = {{a0.x, a0.y, a0.z, a0.w}, {a1.x, a1.y, a1.z, a1.w}};
      float bv[2][4] = {{b0.x, b0.y, b0.z, b0.w}, {b1.x, b1.y, b1.z, b1.w}};
#pragma unroll
      for (int ih = 0; ih < 2; ++ih)
#pragma unroll
        for (int jh = 0; jh < 2; ++jh)
#pragma unroll
          for (int i = 0; i < 4; ++i)
#pragma unroll
            for (int j = 0; j < 4; ++j)
              c[ih][jh][i][j] += av[ih][i] * bv[jh][j];
    }
    __syncthreads();
  }
#pragma unroll
  for (int ih = 0; ih < 2; ++ih)
#pragma unroll
    for (int i = 0; i < 4; ++i) {
      int gr = m0 + ih * 64 + ty * 4 + i;
      if (gr >= M) continue;
#pragma unroll
      for (int jh = 0; jh < 2; ++jh) {
        float4 v = {c[ih][jh][i][0], c[ih][jh][i][1], c[ih][jh][i][2],
                    c[ih][jh][i][3]};
        *(float4*)&C[(size_t)gr * N + n0 + jh * 64 + tx * 4] = v;
      }
    }
}

// ---------------- attention logits: al_s/al_d [N,4] from h [N,256] ----------

__global__ __launch_bounds__(256) void compute_al(const float* __restrict__ h,
                                                  const float* __restrict__ a_src,
                                                  const float* __restrict__ a_dst,
                                                  float* __restrict__ al_s,
                                                  float* __restrict__ al_d,
                                                  int nnodes) {
  int n = blockIdx.x * 4 + (threadIdx.x >> 6);
  if (n >= nnodes) return;
  int l = threadIdx.x & 63;
  float4 hv = *(const float4*)&h[(size_t)n * 256 + l * 4];
  float4 as4 = *(const float4*)&a_src[l * 4];
  float4 ad4 = *(const float4*)&a_dst[l * 4];
  float ps = hv.x * as4.x + hv.y * as4.y + hv.z * as4.z + hv.w * as4.w;
  float pd = hv.x * ad4.x + hv.y * ad4.y + hv.z * ad4.z + hv.w * ad4.w;
#pragma unroll
  for (int off = 1; off < 16; off <<= 1) {
    ps += __shfl_xor(ps, off);
    pd += __shfl_xor(pd, off);
  }
  if ((l & 15) == 0) {
    al_s[n * 4 + (l >> 4)] = ps;
    al_d[n * 4 + (l >> 4)] = pd;
  }
}

// ---------------- per-dst two-pass softmax aggregation (heads=4, C=64) ------
// One wave per destination node. Pass 1: 16 edges x 4 heads in parallel
// compute e -> LDS, running max, 16-lane shuffle-reduce. Pass 2: fixed m, so
// the h[src] gather loop has no serial dependence -> unroll x4 for MLP.

template <bool RELU>
__global__ __launch_bounds__(256) void gat_aggregate(
    const float* __restrict__ h, const float* __restrict__ al_s,
    const float* __restrict__ al_d, const int* __restrict__ row_ptr,
    const int* __restrict__ col_idx, const float* __restrict__ bias,
    float* __restrict__ out, int nnodes) {
  __shared__ float e_lds[4][ECAP * 4];
  int wv = threadIdx.x >> 6;
  int n = blockIdx.x * 4 + wv;
  if (n >= nnodes) return;
  int l = threadIdx.x & 63;
  int hd = l >> 4;
  int sub = l & 15;
  int beg = row_ptr[n], end = row_ptr[n + 1];
  int deg = end - beg;
  float ad = al_d[n * 4 + hd];

  // ---- pass 1: logits + max ----
  float m = -3.0e38f;
  for (int j0 = 0; j0 < deg; j0 += 16) {
    int j = j0 + sub;
    float e = -3.0e38f;
    if (j < deg) {
      int src = col_idx[beg + j];
      e = al_s[src * 4 + hd] + ad;
      e = fmaxf(e, 0.2f * e);  // leaky_relu(0.2)
      if (j < ECAP) e_lds[wv][j * 4 + hd] = e;
    }
    m = fmaxf(m, e);
  }
#pragma unroll
  for (int off = 1; off < 16; off <<= 1) m = fmaxf(m, __shfl_xor(m, off));
  __syncthreads();

  // ---- pass 2: p = exp(e - m), gather-FMA, unrolled x4 ----
  float s = 0.f;
  float4 acc = {0.f, 0.f, 0.f, 0.f};
  int jcap = deg < ECAP ? deg : ECAP;
  int j = 0;
  for (; j + 4 <= jcap; j += 4) {
    int s0 = col_idx[beg + j + 0];
    int s1 = col_idx[beg + j + 1];
    int s2 = col_idx[beg + j + 2];
    int s3 = col_idx[beg + j + 3];
    float4 hv0 = *(const float4*)&h[(size_t)s0 * 256 + l * 4];
    float4 hv1 = *(const float4*)&h[(size_t)s1 * 256 + l * 4];
    float4 hv2 = *(const float4*)&h[(size_t)s2 * 256 + l * 4];
    float4 hv3 = *(const float4*)&h[(size_t)s3 * 256 + l * 4];
    float p0 = __expf(e_lds[wv][(j + 0) * 4 + hd] - m);
    float p1 = __expf(e_lds[wv][(j + 1) * 4 + hd] - m);
    float p2 = __expf(e_lds[wv][(j + 2) * 4 + hd] - m);
    float p3 = __expf(e_lds[wv][(j + 3) * 4 + hd] - m);
    s += (p0 + p1) + (p2 + p3);
    acc.x += p0 * hv0.x + p1 * hv1.x + p2 * hv2.x + p3 * hv3.x;
    acc.y += p0 * hv0.y + p1 * hv1.y + p2 * hv2.y + p3 * hv3.y;
    acc.z += p0 * hv0.z + p1 * hv1.z + p2 * hv2.z + p3 * hv3.z;
    acc.w += p0 * hv0.w + p1 * hv1.w + p2 * hv2.w + p3 * hv3.w;
  }
  for (; j < deg; ++j) {
    int src = col_idx[beg + j];
    float e;
    if (j < ECAP) {
      e = e_lds[wv][j * 4 + hd];
    } else {  // fallback for pathological degree (never hit for this graph)
      e = al_s[src * 4 + hd] + ad;
      e = fmaxf(e, 0.2f * e);
    }
    float p = __expf(e - m);
    s += p;
    float4 hv = *(const float4*)&h[(size_t)src * 256 + l * 4];
    acc.x += p * hv.x;
    acc.y += p * hv.y;
    acc.z += p * hv.z;
    acc.w += p * hv.w;
  }
  float inv = 1.f / (s + 1e-16f);
  float4 bv = *(const float4*)&bias[l * 4];
  float4 o = {acc.x * inv + bv.x, acc.y * inv + bv.y, acc.z * inv + bv.z,
              acc.w * inv + bv.w};
  if (RELU) {
    o.x = fmaxf(o.x, 0.f);
    o.y = fmaxf(o.y, 0.f);
    o.z = fmaxf(o.z, 0.f);
    o.w = fmaxf(o.w, 0.f);
  }
  *(float4*)&out[(size_t)n * 256 + l * 4] = o;
}

// ---------------- layer 3: tiny GEMM (256->5) fused with al3 ----------------

__global__ __launch_bounds__(256) void gemm3_al(const float* __restrict__ Hin,
                                                const float* __restrict__ W3,
                                                const float* __restrict__ a_src3,
                                                const float* __restrict__ a_dst3,
                                                float* __restrict__ h3,
                                                float* __restrict__ al_s,
                                                float* __restrict__ al_d,
                                                int nnodes) {
  int n = blockIdx.x * 4 + (threadIdx.x >> 6);
  if (n >= nnodes) return;
  int l = threadIdx.x & 63;
  float4 hv = *(const float4*)&Hin[(size_t)n * 256 + l * 4];
  float acc[5];
#pragma unroll
  for (int cc = 0; cc < 5; ++cc) {
    acc[cc] = hv.x * W3[(l * 4 + 0) * 5 + cc] + hv.y * W3[(l * 4 + 1) * 5 + cc] +
              hv.z * W3[(l * 4 + 2) * 5 + cc] + hv.w * W3[(l * 4 + 3) * 5 + cc];
  }
#pragma unroll
  for (int cc = 0; cc < 5; ++cc)
#pragma unroll
    for (int off = 32; off; off >>= 1) acc[cc] += __shfl_xor(acc[cc], off);
  if (l == 0) {
    float as = 0.f, adv = 0.f;
#pragma unroll
    for (int cc = 0; cc < 5; ++cc) {
      h3[(size_t)n * 5 + cc] = acc[cc];
      as += acc[cc] * a_src3[cc];
      adv += acc[cc] * a_dst3[cc];
    }
    al_s[n] = as;
    al_d[n] = adv;
  }
}

__global__ __launch_bounds__(256) void gat_aggregate3(
    const float* __restrict__ h3, const float* __restrict__ al_s,
    const float* __restrict__ al_d, const int* __restrict__ row_ptr,
    const int* __restrict__ col_idx, const float* __restrict__ b3,
    float* __restrict__ out, int nnodes) {
  int n = blockIdx.x * 4 + (threadIdx.x >> 6);
  if (n >= nnodes) return;
  int l = threadIdx.x & 63;
  float ad = al_d[n];
  int beg = row_ptr[n], end = row_ptr[n + 1];
  float m = -3.0e38f, s = 0.f, acc = 0.f;
  for (int j = beg; j < end; ++j) {
    int src = col_idx[j];
    float e = al_s[src] + ad;
    e = fmaxf(e, 0.2f * e);
    float mn = fmaxf(m, e);
    float sc = __expf(m - mn);
    float p = __expf(e - mn);
    s = s * sc + p;
    float hv = (l < 5) ? h3[(size_t)src * 5 + l] : 0.f;
    acc = acc * sc + p * hv;
    m = mn;
  }
  if (l < 5) out[(size_t)n * 5 + l] = acc / (s + 1e-16f) + b3[l];
}

// ---------------- launch ----------------

extern "C" void kernel_launch(void* const* d_in, const int* in_sizes, int n_in,
                              void* d_out, int out_size, void* d_ws, size_t ws_size,
                              hipStream_t stream) {
  const float* x = (const float*)d_in[0];
  const int* ei = (const int*)d_in[1];
  const float* W1 = (const float*)d_in[2];
  const float* as1 = (const float*)d_in[3];
  const float* ad1 = (const float*)d_in[4];
  const float* b1 = (const float*)d_in[5];
  const float* W2 = (const float*)d_in[6];
  const float* as2 = (const float*)d_in[7];
  const float* ad2 = (const float*)d_in[8];
  const float* b2 = (const float*)d_in[9];
  const float* W3 = (const float*)d_in[10];
  const float* as3 = (const float*)d_in[11];
  const float* ad3 = (const float*)d_in[12];
  const float* b3 = (const float*)d_in[13];

  int N = in_sizes[0] / 128;  // 50000
  int E = in_sizes[1] / 2;    // 800000
  int tot = E + N;            // 850000

  char* w = (char*)d_ws;
  size_t off = 0;
  auto alloc = [&](size_t bytes) -> void* {
    void* p = w + off;
    off += (bytes + 255) & ~(size_t)255;
    return p;
  };
  float* bufA = (float*)alloc((size_t)N * 256 * 4);
  float* bufB = (float*)alloc((size_t)N * 256 * 4);
  float* h3 = (float*)alloc((size_t)N * 5 * 4);
  float* alS = (float*)alloc((size_t)N * 4 * 4);
  float* alD = (float*)alloc((size_t)N * 4 * 4);
  int* row_ptr = (int*)alloc(((size_t)N + 1) * 4);
  int* nextp = (int*)alloc((size_t)N * 4);
  int* bsums = (int*)alloc(256 * 4);
  int* col_idx = (int*)alloc((size_t)tot * 4);
  (void)ws_size;

  int nbN = (N + 255) / 256;
  int nbE = (tot + 255) / 256;
  int nb4 = (N + 3) / 4;

  // CSR build (counts live in nextp)
  zero_i32<<<nbN, 256, 0, stream>>>(nextp, N);
  edge_histogram<<<nbE, 256, 0, stream>>>(ei, E, N, nextp);
  scan_block<<<nbN, 256, 0, stream>>>(nextp, row_ptr, bsums, N);
  scan_block<<<1, 256, 0, stream>>>(bsums, bsums, nullptr, nbN);
  add_offsets<<<nbN, 256, 0, stream>>>(row_ptr, bsums, nextp, N, tot);
  edge_scatter<<<nbE, 256, 0, stream>>>(ei, E, N, nextp, col_idx);

  dim3 g1((N + TILE_BM - 1) / TILE_BM, 256 / TILE_BN);

  // layer 1
  gemm_f32<<<g1, 256, 0, stream>>>(x, W1, bufA, N, 256, 128);
  compute_al<<<nb4, 256, 0, stream>>>(bufA, as1, ad1, alS, alD, N);
  gat_aggregate<true><<<nb4, 256, 0, stream>>>(bufA, alS, alD, row_ptr, col_idx,
                                               b1, bufB, N);
  // layer 2
  gemm_f32<<<g1, 256, 0, stream>>>(bufB, W2, bufA, N, 256, 256);
  compute_al<<<nb4, 256, 0, stream>>>(bufA, as2, ad2, alS, alD, N);
  gat_aggregate<true><<<nb4, 256, 0, stream>>>(bufA, alS, alD, row_ptr, col_idx,
                                               b2, bufB, N);
  // layer 3
  gemm3_al<<<nb4, 256, 0, stream>>>(bufB, W3, as3, ad3, h3, alS, alD, N);
  gat_aggregate3<<<nb4, 256, 0, stream>>>(h3, alS, alD, row_ptr, col_idx, b3,
                                          (float*)d_out, N);
}

// Round 4
// 571.811 us; speedup vs baseline: 1.2135x; 1.2010x over previous
//
#include <hip/hip_runtime.h>
#include <hip/hip_bf16.h>
#include <cstddef>

// ---------------------------------------------------------------------------
// 3-layer GAT (PyG-style) on MI355X.
// Round 3: h stored as fp16 -> halves the fabric-bound gather traffic
// (fp32 gather was already at the 8-XCD x 51MB private-L2 re-fetch floor).
// ---------------------------------------------------------------------------

typedef _Float16 h4 __attribute__((ext_vector_type(4)));

#define TILE_BM 128
#define TILE_BN 128
#define TILE_KB 16
#define ECAP 96  // LDS-cached logits per node; deg>ECAP falls back to re-gather

// ---------------- CSR build ----------------

__global__ void zero_i32(int* __restrict__ p, int n) {
  int i = blockIdx.x * 256 + threadIdx.x;
  if (i < n) p[i] = 0;
}

__global__ void edge_histogram(const int* __restrict__ ei, int E, int nnodes,
                               int* __restrict__ counts) {
  int e = blockIdx.x * 256 + threadIdx.x;
  int tot = E + nnodes;
  if (e >= tot) return;
  int dst = (e < E) ? ei[E + e] : (e - E);
  atomicAdd(&counts[dst], 1);
}

__global__ void scan_block(const int* __restrict__ in, int* __restrict__ out,
                           int* __restrict__ sums, int n) {
  __shared__ int tmp[256];
  int i = blockIdx.x * 256 + threadIdx.x;
  int v = (i < n) ? in[i] : 0;
  tmp[threadIdx.x] = v;
  __syncthreads();
  for (int off = 1; off < 256; off <<= 1) {
    int t = (threadIdx.x >= off) ? tmp[threadIdx.x - off] : 0;
    __syncthreads();
    tmp[threadIdx.x] += t;
    __syncthreads();
  }
  if (i < n) out[i] = tmp[threadIdx.x] - v;  // exclusive
  if (sums && threadIdx.x == 255) sums[blockIdx.x] = tmp[255];
}

__global__ void add_offsets(int* __restrict__ row_ptr, const int* __restrict__ offs,
                            int* __restrict__ nextp, int n, int total) {
  int i = blockIdx.x * 256 + threadIdx.x;
  if (i < n) {
    int v = row_ptr[i] + offs[blockIdx.x];
    row_ptr[i] = v;
    nextp[i] = v;
  }
  if (i == 0) row_ptr[n] = total;
}

__global__ void edge_scatter(const int* __restrict__ ei, int E, int nnodes,
                             int* __restrict__ nextp, int* __restrict__ col_idx) {
  int e = blockIdx.x * 256 + threadIdx.x;
  int tot = E + nnodes;
  if (e >= tot) return;
  int src = (e < E) ? ei[e] : (e - E);
  int dst = (e < E) ? ei[E + e] : (e - E);
  int pos = atomicAdd(&nextp[dst], 1);
  col_idx[pos] = src;
}

// ---------------- fp32 GEMM, fp16 output: C16[M,N] = A[M,K] @ B[K,N] --------

__global__ __launch_bounds__(256) void gemm_f32_h16(const float* __restrict__ A,
                                                    const float* __restrict__ B,
                                                    _Float16* __restrict__ C16,
                                                    int M, int N, int K) {
  __shared__ float As[TILE_KB][TILE_BM + 4];
  __shared__ float Bs[TILE_KB][TILE_BN];
  int t = threadIdx.x;
  int m0 = blockIdx.x * TILE_BM;
  int n0 = blockIdx.y * TILE_BN;
  int tx = t & 15, ty = t >> 4;

  float c[2][2][4][4];
#pragma unroll
  for (int a = 0; a < 2; ++a)
#pragma unroll
    for (int b = 0; b < 2; ++b)
#pragma unroll
      for (int i = 0; i < 4; ++i)
#pragma unroll
        for (int j = 0; j < 4; ++j) c[a][b][i][j] = 0.f;

  for (int k0 = 0; k0 < K; k0 += TILE_KB) {
#pragma unroll
    for (int r = 0; r < 2; ++r) {
      int idx = t + r * 256;
      int row = idx >> 2;
      int quad = idx & 3;
      float4 v = {0.f, 0.f, 0.f, 0.f};
      int gr = m0 + row;
      if (gr < M) v = *(const float4*)&A[(size_t)gr * K + k0 + quad * 4];
      As[quad * 4 + 0][row] = v.x;
      As[quad * 4 + 1][row] = v.y;
      As[quad * 4 + 2][row] = v.z;
      As[quad * 4 + 3][row] = v.w;
    }
#pragma unroll
    for (int r = 0; r < 2; ++r) {
      int idx = t + r * 256;
      int krow = idx >> 5;
      int q = idx & 31;
      float4 v = *(const float4*)&B[(size_t)(k0 + krow) * N + n0 + q * 4];
      *(float4*)&Bs[krow][q * 4] = v;
    }
    __syncthreads();
#pragma unroll
    for (int k = 0; k < TILE_KB; ++k) {
      float4 a0 = *(const float4*)&As[k][ty * 4];
      float4 a1 = *(const float4*)&As[k][64 + ty * 4];
      float4 b0 = *(const float4*)&Bs[k][tx * 4];
      float4 b1 = *(const float4*)&Bs[k][64 + tx * 4];
      float av[2][4] = {{a0.x, a0.y, a0.z, a0.w}, {a1.x, a1.y, a1.z, a1.w}};
      float bv[2][4] = {{b0.x, b0.y, b0.z, b0.w}, {b1.x, b1.y, b1.z, b1.w}};
#pragma unroll
      for (int ih = 0; ih < 2; ++ih)
#pragma unroll
        for (int jh = 0; jh < 2; ++jh)
#pragma unroll
          for (int i = 0; i < 4; ++i)
#pragma unroll
            for (int j = 0; j < 4; ++j)
              c[ih][jh][i][j] += av[ih][i] * bv[jh][j];
    }
    __syncthreads();
  }
#pragma unroll
  for (int ih = 0; ih < 2; ++ih)
#pragma unroll
    for (int i = 0; i < 4; ++i) {
      int gr = m0 + ih * 64 + ty * 4 + i;
      if (gr >= M) continue;
#pragma unroll
      for (int jh = 0; jh < 2; ++jh) {
        h4 v = {(_Float16)c[ih][jh][i][0], (_Float16)c[ih][jh][i][1],
                (_Float16)c[ih][jh][i][2], (_Float16)c[ih][jh][i][3]};
        *(h4*)&C16[(size_t)gr * N + n0 + jh * 64 + tx * 4] = v;
      }
    }
}

// ---------------- attention logits: al_s/al_d [N,4] from h16 [N,256] --------

__global__ __launch_bounds__(256) void compute_al(const _Float16* __restrict__ h,
                                                  const float* __restrict__ a_src,
                                                  const float* __restrict__ a_dst,
                                                  float* __restrict__ al_s,
                                                  float* __restrict__ al_d,
                                                  int nnodes) {
  int n = blockIdx.x * 4 + (threadIdx.x >> 6);
  if (n >= nnodes) return;
  int l = threadIdx.x & 63;
  h4 hv4 = *(const h4*)&h[(size_t)n * 256 + l * 4];
  float4 as4 = *(const float4*)&a_src[l * 4];
  float4 ad4 = *(const float4*)&a_dst[l * 4];
  float hx = (float)hv4[0], hy = (float)hv4[1], hz = (float)hv4[2],
        hw = (float)hv4[3];
  float ps = hx * as4.x + hy * as4.y + hz * as4.z + hw * as4.w;
  float pd = hx * ad4.x + hy * ad4.y + hz * ad4.z + hw * ad4.w;
#pragma unroll
  for (int off = 1; off < 16; off <<= 1) {
    ps += __shfl_xor(ps, off);
    pd += __shfl_xor(pd, off);
  }
  if ((l & 15) == 0) {
    al_s[n * 4 + (l >> 4)] = ps;
    al_d[n * 4 + (l >> 4)] = pd;
  }
}

// ---------------- per-dst two-pass softmax aggregation (heads=4, C=64) ------
// One wave per destination node. Pass 1: 16 edges x 4 heads in parallel
// compute e -> LDS, shuffle-reduce max. Pass 2: fixed m -> no serial chain;
// fp16 gather (512B/edge/wave), unrolled x8 for memory-level parallelism.

template <bool RELU>
__global__ __launch_bounds__(256) void gat_aggregate(
    const _Float16* __restrict__ h, const float* __restrict__ al_s,
    const float* __restrict__ al_d, const int* __restrict__ row_ptr,
    const int* __restrict__ col_idx, const float* __restrict__ bias,
    float* __restrict__ out, int nnodes) {
  __shared__ float e_lds[4][ECAP * 4];
  int wv = threadIdx.x >> 6;
  int n = blockIdx.x * 4 + wv;
  if (n >= nnodes) return;
  int l = threadIdx.x & 63;
  int hd = l >> 4;
  int sub = l & 15;
  int beg = row_ptr[n], end = row_ptr[n + 1];
  int deg = end - beg;
  float ad = al_d[n * 4 + hd];

  // ---- pass 1: logits + max ----
  float m = -3.0e38f;
  for (int j0 = 0; j0 < deg; j0 += 16) {
    int j = j0 + sub;
    float e = -3.0e38f;
    if (j < deg) {
      int src = col_idx[beg + j];
      e = al_s[src * 4 + hd] + ad;
      e = fmaxf(e, 0.2f * e);  // leaky_relu(0.2)
      if (j < ECAP) e_lds[wv][j * 4 + hd] = e;
    }
    m = fmaxf(m, e);
  }
#pragma unroll
  for (int off = 1; off < 16; off <<= 1) m = fmaxf(m, __shfl_xor(m, off));
  __syncthreads();

  // ---- pass 2: p = exp(e - m), fp16 gather-FMA, unrolled x8 ----
  float s = 0.f;
  float4 acc = {0.f, 0.f, 0.f, 0.f};
  int jcap = deg < ECAP ? deg : ECAP;
  int j = 0;
  for (; j + 8 <= jcap; j += 8) {
    int si[8];
    h4 hv[8];
    float p[8];
#pragma unroll
    for (int u = 0; u < 8; ++u) si[u] = col_idx[beg + j + u];
#pragma unroll
    for (int u = 0; u < 8; ++u)
      hv[u] = *(const h4*)&h[(size_t)si[u] * 256 + l * 4];
#pragma unroll
    for (int u = 0; u < 8; ++u) p[u] = __expf(e_lds[wv][(j + u) * 4 + hd] - m);
#pragma unroll
    for (int u = 0; u < 8; ++u) {
      s += p[u];
      acc.x += p[u] * (float)hv[u][0];
      acc.y += p[u] * (float)hv[u][1];
      acc.z += p[u] * (float)hv[u][2];
      acc.w += p[u] * (float)hv[u][3];
    }
  }
  for (; j < deg; ++j) {
    int src = col_idx[beg + j];
    float e;
    if (j < ECAP) {
      e = e_lds[wv][j * 4 + hd];
    } else {  // fallback for pathological degree
      e = al_s[src * 4 + hd] + ad;
      e = fmaxf(e, 0.2f * e);
    }
    float p = __expf(e - m);
    s += p;
    h4 hv = *(const h4*)&h[(size_t)src * 256 + l * 4];
    acc.x += p * (float)hv[0];
    acc.y += p * (float)hv[1];
    acc.z += p * (float)hv[2];
    acc.w += p * (float)hv[3];
  }
  float inv = 1.f / (s + 1e-16f);
  float4 bv = *(const float4*)&bias[l * 4];
  float4 o = {acc.x * inv + bv.x, acc.y * inv + bv.y, acc.z * inv + bv.z,
              acc.w * inv + bv.w};
  if (RELU) {
    o.x = fmaxf(o.x, 0.f);
    o.y = fmaxf(o.y, 0.f);
    o.z = fmaxf(o.z, 0.f);
    o.w = fmaxf(o.w, 0.f);
  }
  *(float4*)&out[(size_t)n * 256 + l * 4] = o;
}

// ---------------- layer 3: tiny GEMM (256->5) fused with al3 ----------------

__global__ __launch_bounds__(256) void gemm3_al(const float* __restrict__ Hin,
                                                const float* __restrict__ W3,
                                                const float* __restrict__ a_src3,
                                                const float* __restrict__ a_dst3,
                                                float* __restrict__ h3,
                                                float* __restrict__ al_s,
                                                float* __restrict__ al_d,
                                                int nnodes) {
  int n = blockIdx.x * 4 + (threadIdx.x >> 6);
  if (n >= nnodes) return;
  int l = threadIdx.x & 63;
  float4 hv = *(const float4*)&Hin[(size_t)n * 256 + l * 4];
  float acc[5];
#pragma unroll
  for (int cc = 0; cc < 5; ++cc) {
    acc[cc] = hv.x * W3[(l * 4 + 0) * 5 + cc] + hv.y * W3[(l * 4 + 1) * 5 + cc] +
              hv.z * W3[(l * 4 + 2) * 5 + cc] + hv.w * W3[(l * 4 + 3) * 5 + cc];
  }
#pragma unroll
  for (int cc = 0; cc < 5; ++cc)
#pragma unroll
    for (int off = 32; off; off >>= 1) acc[cc] += __shfl_xor(acc[cc], off);
  if (l == 0) {
    float as = 0.f, adv = 0.f;
#pragma unroll
    for (int cc = 0; cc < 5; ++cc) {
      h3[(size_t)n * 5 + cc] = acc[cc];
      as += acc[cc] * a_src3[cc];
      adv += acc[cc] * a_dst3[cc];
    }
    al_s[n] = as;
    al_d[n] = adv;
  }
}

// two-pass (parallel logits, no serial exp-rescale chain), heads=1, C=5

__global__ __launch_bounds__(256) void gat_aggregate3(
    const float* __restrict__ h3, const float* __restrict__ al_s,
    const float* __restrict__ al_d, const int* __restrict__ row_ptr,
    const int* __restrict__ col_idx, const float* __restrict__ b3,
    float* __restrict__ out, int nnodes) {
  __shared__ float e_lds[4][ECAP];
  int wv = threadIdx.x >> 6;
  int n = blockIdx.x * 4 + wv;
  if (n >= nnodes) return;
  int l = threadIdx.x & 63;
  int beg = row_ptr[n], end = row_ptr[n + 1];
  int deg = end - beg;
  float ad = al_d[n];

  // pass 1: all 64 lanes compute logits in parallel
  float m = -3.0e38f;
  for (int j0 = 0; j0 < deg; j0 += 64) {
    int j = j0 + l;
    float e = -3.0e38f;
    if (j < deg) {
      int src = col_idx[beg + j];
      e = al_s[src] + ad;
      e = fmaxf(e, 0.2f * e);
      if (j < ECAP) e_lds[wv][j] = e;
    }
    m = fmaxf(m, e);
  }
#pragma unroll
  for (int off = 1; off < 64; off <<= 1) m = fmaxf(m, __shfl_xor(m, off));

  // s: parallel partial sums over LDS/recomputed logits
  float sp = 0.f;
  for (int j = l; j < deg; j += 64) {
    float e;
    if (j < ECAP) {
      e = e_lds[wv][j];
    } else {
      int src = col_idx[beg + j];
      e = al_s[src] + ad;
      e = fmaxf(e, 0.2f * e);
    }
    sp += __expf(e - m);
  }
#pragma unroll
  for (int off = 1; off < 64; off <<= 1) sp += __shfl_xor(sp, off);
  float s = sp;

  // pass 2: lanes 0..4 gather h3 and accumulate (h3 is 1MB, L2-resident)
  float acc = 0.f;
  if (l < 5) {
    for (int j = 0; j < deg; ++j) {
      float e;
      if (j < ECAP) {
        e = e_lds[wv][j];
      } else {
        int src0 = col_idx[beg + j];
        e = al_s[src0] + ad;
        e = fmaxf(e, 0.2f * e);
      }
      float p = __expf(e - m);
      int src = col_idx[beg + j];
      acc += p * h3[(size_t)src * 5 + l];
    }
    out[(size_t)n * 5 + l] = acc / (s + 1e-16f) + b3[l];
  }
}

// ---------------- launch ----------------

extern "C" void kernel_launch(void* const* d_in, const int* in_sizes, int n_in,
                              void* d_out, int out_size, void* d_ws, size_t ws_size,
                              hipStream_t stream) {
  const float* x = (const float*)d_in[0];
  const int* ei = (const int*)d_in[1];
  const float* W1 = (const float*)d_in[2];
  const float* as1 = (const float*)d_in[3];
  const float* ad1 = (const float*)d_in[4];
  const float* b1 = (const float*)d_in[5];
  const float* W2 = (const float*)d_in[6];
  const float* as2 = (const float*)d_in[7];
  const float* ad2 = (const float*)d_in[8];
  const float* b2 = (const float*)d_in[9];
  const float* W3 = (const float*)d_in[10];
  const float* as3 = (const float*)d_in[11];
  const float* ad3 = (const float*)d_in[12];
  const float* b3 = (const float*)d_in[13];

  int N = in_sizes[0] / 128;  // 50000
  int E = in_sizes[1] / 2;    // 800000
  int tot = E + N;            // 850000

  char* w = (char*)d_ws;
  size_t off = 0;
  auto alloc = [&](size_t bytes) -> void* {
    void* p = w + off;
    off += (bytes + 255) & ~(size_t)255;
    return p;
  };
  _Float16* h16 = (_Float16*)alloc((size_t)N * 256 * 2);
  float* bufB = (float*)alloc((size_t)N * 256 * 4);
  float* bufC = (float*)alloc((size_t)N * 256 * 4);
  float* h3 = (float*)alloc((size_t)N * 5 * 4);
  float* alS = (float*)alloc((size_t)N * 4 * 4);
  float* alD = (float*)alloc((size_t)N * 4 * 4);
  int* row_ptr = (int*)alloc(((size_t)N + 1) * 4);
  int* nextp = (int*)alloc((size_t)N * 4);
  int* bsums = (int*)alloc(256 * 4);
  int* col_idx = (int*)alloc((size_t)tot * 4);
  (void)ws_size;

  int nbN = (N + 255) / 256;
  int nbE = (tot + 255) / 256;
  int nb4 = (N + 3) / 4;

  // CSR build (counts live in nextp)
  zero_i32<<<nbN, 256, 0, stream>>>(nextp, N);
  edge_histogram<<<nbE, 256, 0, stream>>>(ei, E, N, nextp);
  scan_block<<<nbN, 256, 0, stream>>>(nextp, row_ptr, bsums, N);
  scan_block<<<1, 256, 0, stream>>>(bsums, bsums, nullptr, nbN);
  add_offsets<<<nbN, 256, 0, stream>>>(row_ptr, bsums, nextp, N, tot);
  edge_scatter<<<nbE, 256, 0, stream>>>(ei, E, N, nextp, col_idx);

  dim3 g1((N + TILE_BM - 1) / TILE_BM, 256 / TILE_BN);

  // layer 1
  gemm_f32_h16<<<g1, 256, 0, stream>>>(x, W1, h16, N, 256, 128);
  compute_al<<<nb4, 256, 0, stream>>>(h16, as1, ad1, alS, alD, N);
  gat_aggregate<true><<<nb4, 256, 0, stream>>>(h16, alS, alD, row_ptr, col_idx,
                                               b1, bufB, N);
  // layer 2
  gemm_f32_h16<<<g1, 256, 0, stream>>>(bufB, W2, h16, N, 256, 256);
  compute_al<<<nb4, 256, 0, stream>>>(h16, as2, ad2, alS, alD, N);
  gat_aggregate<true><<<nb4, 256, 0, stream>>>(h16, alS, alD, row_ptr, col_idx,
                                               b2, bufC, N);
  // layer 3
  gemm3_al<<<nb4, 256, 0, stream>>>(bufC, W3, as3, ad3, h3, alS, alD, N);
  gat_aggregate3<<<nb4, 256, 0, stream>>>(h3, alS, alD, row_ptr, col_idx, b3,
                                          (float*)d_out, N);
}